// Round 22
// baseline (142.730 us; speedup 1.0000x reference)
//
#include <hip/hip_runtime.h>

#define S_LEN 512
#define BATCH 64
#define HDIM  1024
#define TWOH  2048
#define EMB   512
#define KDIM  2560      // 2H + EMB
#define KTOT  3584      // 2H + EMB + H
#define VOUT  32000

// ws layout (float offsets)
#define WS_MS    64
#define WS_CTX   2112                        // f32 [64][16][2048] = 2,097,152 floats
#define WS_GP    WS_CTX                      // gate partials [8][4096][64] f32 — aliases dead ctx
#define WS_RNNB  (WS_CTX + 64*16*2048)       // bf16 [64][3584] = 114,688 floats
#define WS_HB16  (WS_RNNB + 114688)          // bf16 [64][1024] = 32,768 floats

typedef __attribute__((ext_vector_type(8))) short bf16x8;
typedef __attribute__((ext_vector_type(4))) float f32x4;

__device__ __forceinline__ float sigmoidf_(float x) { return 1.f/(1.f+__expf(-x)); }

// RNE float -> bf16 (finite inputs)
__device__ __forceinline__ unsigned short f2bf(float f) {
  union { float f; unsigned u; } v; v.f = f;
  return (unsigned short)((v.u + 0x7fffu + ((v.u >> 16) & 1u)) >> 16);
}

// K1 v3: single-pass online-softmax context, row-pipelined, hb inline.
__global__ __launch_bounds__(256) void k_attn(const float* __restrict__ enc,
                                              const float* __restrict__ eW,
                                              const float* __restrict__ eb,
                                              const float* __restrict__ hidden,
                                              float* __restrict__ ws_ms,
                                              float* __restrict__ ws_ctx) {
  __shared__ float lds_ms[4][2];
  __shared__ float lds_ctx[4][2048];
  const int lane  = threadIdx.x & 63;
  const int wave  = threadIdx.x >> 6;
  const int chunk = blockIdx.x;   // 0..15
  const int b     = blockIdx.y;   // 0..63

  float hba = 0.f;
  for (int k = lane; k < HDIM; k += 64) hba += hidden[b*HDIM + k] * eW[k];
#pragma unroll
  for (int st = 32; st >= 1; st >>= 1) hba += __shfl_xor(hba, st, 64);
  const float hb = hba + eb[0];

  float4 w4[8];
#pragma unroll
  for (int k = 0; k < 8; ++k)
    w4[k] = *reinterpret_cast<const float4*>(eW + HDIM + 4*lane + 256*k);

  const int s0 = chunk*32 + wave*8;
  const float* base = enc + ((size_t)(s0*BATCH + b))*TWOH + 4*lane;

  float m = 0.f, ssum = 0.f;      // relu => e >= 0
  float4 ctx[8];
#pragma unroll
  for (int k = 0; k < 8; ++k) ctx[k] = make_float4(0.f, 0.f, 0.f, 0.f);

  float4 va[8], vb[8];
#pragma unroll
  for (int k = 0; k < 8; ++k) va[k] = *reinterpret_cast<const float4*>(base + 256*k);

#define ATTN_STEP(VCUR, VNXT, I)                                              \
  {                                                                           \
    if ((I) < 7) {                                                            \
      const float* pn = base + (size_t)((I)+1)*BATCH*TWOH;                    \
      _Pragma("unroll")                                                       \
      for (int k = 0; k < 8; ++k)                                             \
        VNXT[k] = *reinterpret_cast<const float4*>(pn + 256*k);               \
    }                                                                         \
    float a = 0.f;                                                            \
    _Pragma("unroll")                                                         \
    for (int k = 0; k < 8; ++k)                                               \
      a += VCUR[k].x*w4[k].x + VCUR[k].y*w4[k].y +                            \
           VCUR[k].z*w4[k].z + VCUR[k].w*w4[k].w;                             \
    _Pragma("unroll")                                                         \
    for (int st = 1; st < 64; st <<= 1) a += __shfl_xor(a, st, 64);           \
    const float e = fmaxf(a + hb, 0.f);                                       \
    if (e > m) {                                                              \
      const float sc = __expf(m - e);                                         \
      ssum = ssum*sc + 1.f;                                                   \
      _Pragma("unroll")                                                       \
      for (int k = 0; k < 8; ++k) {                                           \
        ctx[k].x = fmaf(ctx[k].x, sc, VCUR[k].x);                             \
        ctx[k].y = fmaf(ctx[k].y, sc, VCUR[k].y);                             \
        ctx[k].z = fmaf(ctx[k].z, sc, VCUR[k].z);                             \
        ctx[k].w = fmaf(ctx[k].w, sc, VCUR[k].w);                             \
      }                                                                       \
      m = e;                                                                  \
    } else {                                                                  \
      const float pw = __expf(e - m);                                         \
      ssum += pw;                                                             \
      _Pragma("unroll")                                                       \
      for (int k = 0; k < 8; ++k) {                                           \
        ctx[k].x = fmaf(pw, VCUR[k].x, ctx[k].x);                             \
        ctx[k].y = fmaf(pw, VCUR[k].y, ctx[k].y);                             \
        ctx[k].z = fmaf(pw, VCUR[k].z, ctx[k].z);                             \
        ctx[k].w = fmaf(pw, VCUR[k].w, ctx[k].w);                             \
      }                                                                       \
    }                                                                         \
  }

  ATTN_STEP(va, vb, 0)
  ATTN_STEP(vb, va, 1)
  ATTN_STEP(va, vb, 2)
  ATTN_STEP(vb, va, 3)
  ATTN_STEP(va, vb, 4)
  ATTN_STEP(vb, va, 5)
  ATTN_STEP(va, vb, 6)
  ATTN_STEP(vb, va, 7)
#undef ATTN_STEP

  if (lane == 0) { lds_ms[wave][0] = m; lds_ms[wave][1] = ssum; }
  __syncthreads();
  const float M = fmaxf(fmaxf(lds_ms[0][0], lds_ms[1][0]),
                        fmaxf(lds_ms[2][0], lds_ms[3][0]));
  const float wsc = __expf(m - M);
  float ssum_c = 0.f;
#pragma unroll
  for (int w = 0; w < 4; ++w) ssum_c += __expf(lds_ms[w][0] - M) * lds_ms[w][1];
#pragma unroll
  for (int k = 0; k < 8; ++k) {
    float4 c = ctx[k];
    c.x *= wsc; c.y *= wsc; c.z *= wsc; c.w *= wsc;
    *reinterpret_cast<float4*>(&lds_ctx[wave][4*lane + 256*k]) = c;
  }
  __syncthreads();
  float* outp = ws_ctx + ((size_t)b*16 + chunk)*TWOH;
  for (int d = threadIdx.x; d < TWOH; d += 256)
    outp[d] = lds_ctx[0][d] + lds_ctx[1][d] + lds_ctx[2][d] + lds_ctx[3][d];
  if (threadIdx.x == 0) {
    ws_ms[((size_t)b*16 + chunk)*2]     = M;
    ws_ms[((size_t)b*16 + chunk)*2 + 1] = ssum_c;
  }
}

// K2 v4: parallel combine. Grid (14 kchunks x 64 b), 1 thread = 1 output elem.
__global__ __launch_bounds__(256) void k_combine(const float* __restrict__ ws_ms,
                                                 const float* __restrict__ ws_ctx,
                                                 const float* __restrict__ hidden,
                                                 const float* __restrict__ emb_table,
                                                 const int* __restrict__ x,
                                                 unsigned short* __restrict__ rnnB) {
  const int b = blockIdx.y;
  const int k = blockIdx.x*256 + threadIdx.x;   // 0..3583
  unsigned short* rb = rnnB + (size_t)b*KTOT;

  if (k < TWOH) {
    float mc[16], sc[16];
#pragma unroll
    for (int c = 0; c < 16; ++c) {
      mc[c] = ws_ms[(b*16 + c)*2];
      sc[c] = ws_ms[(b*16 + c)*2 + 1];
    }
    float M = mc[0];
#pragma unroll
    for (int c = 1; c < 16; ++c) M = fmaxf(M, mc[c]);
    float wc[16], Ssum = 0.f;
#pragma unroll
    for (int c = 0; c < 16; ++c) { wc[c] = __expf(mc[c] - M); Ssum += wc[c]*sc[c]; }
    const float inv = 1.f / Ssum;
    float a = 0.f;
#pragma unroll
    for (int c = 0; c < 16; ++c) a += wc[c] * ws_ctx[((size_t)b*16 + c)*TWOH + k];
    rb[k] = f2bf(a * inv);
  } else if (k < KDIM) {
    const int xb = x[b];
    rb[k] = f2bf(emb_table[(size_t)xb*EMB + (k - TWOH)]);
  } else {
    rb[k] = f2bf(hidden[b*HDIM + (k - KDIM)]);
  }
}

// K3 v9: LDS-staged MFMA gate GEMM with 2-deep staging pipeline (two reg
// sets): at chunk c issue GLOAD(c+2), SWRITE(c+1) from the set loaded at c-1.
// Arithmetic order identical to v8 -> same absmax.
__global__ __launch_bounds__(256) void k_gates(const unsigned short* __restrict__ rnnB,
                                               const float* __restrict__ W_ih,
                                               const float* __restrict__ W_hh,
                                               float* __restrict__ ws_gp) {
  __shared__ unsigned short lds_a[2][64*64];   // 2 x 8KB
  const int tid  = threadIdx.x;
  const int lane = tid & 63;
  const int wave = tid >> 6;
  const int part = blockIdx.x & 7;     // k-part: 448 each
  const int rg   = blockIdx.x >> 3;    // 0..63
  const int j0   = rg*64;              // block's first gate row
  const int mlo  = lane & 15;
  const int kg   = lane >> 4;
  const int srow = tid >> 4;           // staging row 0..15 (+jj*16)
  const int scol = (tid & 15) * 4;     // staging col (floats)

  const unsigned short* rp0 = rnnB + (size_t)mlo*KTOT;

  f32x4 acc0 = {0.f,0.f,0.f,0.f}, acc1 = acc0, acc2 = acc0, acc3 = acc0;
  float4 stA[4], stB[4];

#define G_GLOAD(ST, C)                                                        \
  {                                                                           \
    const int kb = part*448 + (C)*64;                                         \
    _Pragma("unroll")                                                         \
    for (int jj = 0; jj < 4; ++jj) {                                          \
      const int r = j0 + srow + jj*16;                                        \
      const float* wrow = (kb < KDIM)                                         \
          ? (W_ih + (size_t)r*KDIM + kb + scol)                               \
          : (W_hh + (size_t)r*HDIM + (kb - KDIM) + scol);                     \
      ST[jj] = *reinterpret_cast<const float4*>(wrow);                        \
    }                                                                         \
  }

#define G_SWRITE(ST, BUF)                                                     \
  _Pragma("unroll")                                                           \
  for (int jj = 0; jj < 4; ++jj) {                                            \
    const int r = srow + jj*16;                                               \
    unsigned short tmp[4];                                                    \
    tmp[0] = f2bf(ST[jj].x); tmp[1] = f2bf(ST[jj].y);                         \
    tmp[2] = f2bf(ST[jj].z); tmp[3] = f2bf(ST[jj].w);                         \
    const int boff = r*128 + ((scol*2) ^ ((r & 7) << 4));                     \
    *reinterpret_cast<uint2*>(reinterpret_cast<char*>(lds_a[BUF]) + boff) =   \
        *reinterpret_cast<const uint2*>(tmp);                                 \
  }

  G_GLOAD(stA, 0)
  G_SWRITE(stA, 0)
  G_GLOAD(stB, 1)
  __syncthreads();

  const int arow = wave*16 + mlo;
  const int abase = arow*128;
  const int asw  = (arow & 7) << 4;

#pragma unroll
  for (int c = 0; c < 7; ++c) {
    const int cur = c & 1;
    if (c + 2 < 7) {
      if ((c & 1) == 0) { G_GLOAD(stA, c+2) } else { G_GLOAD(stB, c+2) }
    }

    const bf16x8 af0 = *reinterpret_cast<const bf16x8*>(
        reinterpret_cast<const char*>(lds_a[cur]) + abase + ((kg*16) ^ asw));
    const bf16x8 af1 = *reinterpret_cast<const bf16x8*>(
        reinterpret_cast<const char*>(lds_a[cur]) + abase + ((64 + kg*16) ^ asw));

    const size_t K0 = (size_t)part*448 + c*64 + kg*8;
    const bf16x8 b00 = *reinterpret_cast<const bf16x8*>(rp0 + K0);
    const bf16x8 b10 = *reinterpret_cast<const bf16x8*>(rp0 + 16*KTOT + K0);
    const bf16x8 b20 = *reinterpret_cast<const bf16x8*>(rp0 + 32*KTOT + K0);
    const bf16x8 b30 = *reinterpret_cast<const bf16x8*>(rp0 + 48*KTOT + K0);
    const bf16x8 b01 = *reinterpret_cast<const bf16x8*>(rp0 + K0 + 32);
    const bf16x8 b11 = *reinterpret_cast<const bf16x8*>(rp0 + 16*KTOT + K0 + 32);
    const bf16x8 b21 = *reinterpret_cast<const bf16x8*>(rp0 + 32*KTOT + K0 + 32);
    const bf16x8 b31 = *reinterpret_cast<const bf16x8*>(rp0 + 48*KTOT + K0 + 32);

    acc0 = __builtin_amdgcn_mfma_f32_16x16x32_bf16(af0, b00, acc0, 0, 0, 0);
    acc1 = __builtin_amdgcn_mfma_f32_16x16x32_bf16(af0, b10, acc1, 0, 0, 0);
    acc2 = __builtin_amdgcn_mfma_f32_16x16x32_bf16(af0, b20, acc2, 0, 0, 0);
    acc3 = __builtin_amdgcn_mfma_f32_16x16x32_bf16(af0, b30, acc3, 0, 0, 0);
    acc0 = __builtin_amdgcn_mfma_f32_16x16x32_bf16(af1, b01, acc0, 0, 0, 0);
    acc1 = __builtin_amdgcn_mfma_f32_16x16x32_bf16(af1, b11, acc1, 0, 0, 0);
    acc2 = __builtin_amdgcn_mfma_f32_16x16x32_bf16(af1, b21, acc2, 0, 0, 0);
    acc3 = __builtin_amdgcn_mfma_f32_16x16x32_bf16(af1, b31, acc3, 0, 0, 0);

    if (c + 1 < 7) {
      if ((c & 1) == 0) { G_SWRITE(stB, cur ^ 1) } else { G_SWRITE(stA, cur ^ 1) }
    }
    __syncthreads();
  }
#undef G_GLOAD
#undef G_SWRITE

  const int mbase = j0 + wave*16 + kg*4;
#define G_ST(ACC, N)                                                          \
  {                                                                           \
    _Pragma("unroll")                                                         \
    for (int jj = 0; jj < 4; ++jj)                                            \
      ws_gp[((size_t)part*4096 + mbase + jj)*64 + ((N)*16 + mlo)] = ACC[jj];  \
  }
  G_ST(acc0, 0) G_ST(acc1, 1) G_ST(acc2, 2) G_ST(acc3, 3)
#undef G_ST
}

// K3b: sum 8 partials + biases, LSTM pointwise; emit h as f32 outs + bf16 hB.
__global__ __launch_bounds__(256) void k_lstm(const float* __restrict__ ws_gp,
                                              const float* __restrict__ b_ih,
                                              const float* __restrict__ b_hh,
                                              const float* __restrict__ cell,
                                              float* __restrict__ out_h,
                                              float* __restrict__ out_c,
                                              unsigned short* __restrict__ hB) {
  const int id = blockIdx.x*256 + threadIdx.x;  // 65536
  const int h = id >> 6, b = id & 63;
  float g[4];
#pragma unroll
  for (int gg = 0; gg < 4; ++gg) {
    const int j = gg*1024 + h;
    float v = b_ih[j] + b_hh[j];
#pragma unroll
    for (int p = 0; p < 8; ++p) v += ws_gp[((size_t)p*4096 + j)*64 + b];
    g[gg] = v;
  }
  const float iv = sigmoidf_(g[0]);
  const float fv = sigmoidf_(g[1]);
  const float gv = tanhf(g[2]);
  const float ov = sigmoidf_(g[3]);
  const float cold = cell[b*HDIM + h];
  const float cn = fmaf(fv, cold, iv*gv);
  const float hn = ov * tanhf(cn);
  out_h[b*HDIM + h] = hn;
  out_c[b*HDIM + h] = cn;
  hB[(size_t)b*HDIM + h] = f2bf(hn);
}

// K4 v13: LDS-staged MFMA fc GEMM with 2-deep staging pipeline (two reg sets).
// Arithmetic order identical to v12 -> same absmax.
__global__ __launch_bounds__(256) void k_fc(const unsigned short* __restrict__ hB,
                                            const float* __restrict__ fc_W,
                                            const float* __restrict__ fc_b,
                                            float* __restrict__ preds) {
  __shared__ unsigned short lds_a[2][64*64];   // 2 x 8KB
  const int tid  = threadIdx.x;
  const int lane = tid & 63;
  const int wave = tid >> 6;
  const int row0b = blockIdx.x * 64;           // grid 500 -> 32000 rows
  const int mlo  = lane & 15;
  const int kg   = lane >> 4;
  const int srow = tid >> 4;                   // staging row 0..15 (+j*16)
  const int scol = (tid & 15) * 4;             // staging col (floats)

  const unsigned short* hp = hB + (size_t)mlo*HDIM + kg*8;

  f32x4 acc0 = {0.f,0.f,0.f,0.f}, acc1 = acc0, acc2 = acc0, acc3 = acc0;
  float4 stA[4], stB[4];

#define FC_GLOAD(ST, C)                                                       \
  _Pragma("unroll")                                                           \
  for (int jj = 0; jj < 4; ++jj)                                              \
    ST[jj] = *reinterpret_cast<const float4*>(                                \
        fc_W + (size_t)(row0b + srow + jj*16)*HDIM + (C)*64 + scol);

#define FC_SWRITE(ST, BUF)                                                    \
  _Pragma("unroll")                                                           \
  for (int jj = 0; jj < 4; ++jj) {                                            \
    const int r = srow + jj*16;                                               \
    unsigned short tmp[4];                                                    \
    tmp[0] = f2bf(ST[jj].x); tmp[1] = f2bf(ST[jj].y);                         \
    tmp[2] = f2bf(ST[jj].z); tmp[3] = f2bf(ST[jj].w);                         \
    const int boff = r*128 + ((scol*2) ^ ((r & 7) << 4));                     \
    *reinterpret_cast<uint2*>(reinterpret_cast<char*>(lds_a[BUF]) + boff) =   \
        *reinterpret_cast<const uint2*>(tmp);                                 \
  }

  FC_GLOAD(stA, 0)
  FC_SWRITE(stA, 0)
  FC_GLOAD(stB, 1)
  __syncthreads();

  const int arow = wave*16 + mlo;
  const int abase = arow*128;
  const int asw  = (arow & 7) << 4;

#pragma unroll
  for (int c = 0; c < 16; ++c) {
    const int cur = c & 1;
    if (c + 2 < 16) {
      if ((c & 1) == 0) { FC_GLOAD(stA, c+2) } else { FC_GLOAD(stB, c+2) }
    }

    const bf16x8 af0 = *reinterpret_cast<const bf16x8*>(
        reinterpret_cast<const char*>(lds_a[cur]) + abase + ((kg*16) ^ asw));
    const bf16x8 af1 = *reinterpret_cast<const bf16x8*>(
        reinterpret_cast<const char*>(lds_a[cur]) + abase + ((64 + kg*16) ^ asw));

    const int K0 = c*64;
    const bf16x8 b00 = *reinterpret_cast<const bf16x8*>(hp + K0);
    const bf16x8 b10 = *reinterpret_cast<const bf16x8*>(hp + 16*HDIM + K0);
    const bf16x8 b20 = *reinterpret_cast<const bf16x8*>(hp + 32*HDIM + K0);
    const bf16x8 b30 = *reinterpret_cast<const bf16x8*>(hp + 48*HDIM + K0);
    const bf16x8 b01 = *reinterpret_cast<const bf16x8*>(hp + K0 + 32);
    const bf16x8 b11 = *reinterpret_cast<const bf16x8*>(hp + 16*HDIM + K0 + 32);
    const bf16x8 b21 = *reinterpret_cast<const bf16x8*>(hp + 32*HDIM + K0 + 32);
    const bf16x8 b31 = *reinterpret_cast<const bf16x8*>(hp + 48*HDIM + K0 + 32);

    acc0 = __builtin_amdgcn_mfma_f32_16x16x32_bf16(af0, b00, acc0, 0, 0, 0);
    acc1 = __builtin_amdgcn_mfma_f32_16x16x32_bf16(af0, b10, acc1, 0, 0, 0);
    acc2 = __builtin_amdgcn_mfma_f32_16x16x32_bf16(af0, b20, acc2, 0, 0, 0);
    acc3 = __builtin_amdgcn_mfma_f32_16x16x32_bf16(af0, b30, acc3, 0, 0, 0);
    acc0 = __builtin_amdgcn_mfma_f32_16x16x32_bf16(af1, b01, acc0, 0, 0, 0);
    acc1 = __builtin_amdgcn_mfma_f32_16x16x32_bf16(af1, b11, acc1, 0, 0, 0);
    acc2 = __builtin_amdgcn_mfma_f32_16x16x32_bf16(af1, b21, acc2, 0, 0, 0);
    acc3 = __builtin_amdgcn_mfma_f32_16x16x32_bf16(af1, b31, acc3, 0, 0, 0);

    if (c + 1 < 16) {
      if ((c & 1) == 0) { FC_SWRITE(stB, cur ^ 1) } else { FC_SWRITE(stA, cur ^ 1) }
    }
    __syncthreads();
  }
#undef FC_GLOAD
#undef FC_SWRITE

  const int mbase = row0b + wave*16 + kg*4;
  const float4 bias = make_float4(fc_b[mbase], fc_b[mbase+1],
                                  fc_b[mbase+2], fc_b[mbase+3]);
#define FC_STORE(ACC, N)                                                      \
  {                                                                           \
    float4 stv = make_float4(ACC[0] + bias.x, ACC[1] + bias.y,                \
                             ACC[2] + bias.z, ACC[3] + bias.w);               \
    *reinterpret_cast<float4*>(preds + (size_t)((N)*16 + mlo)*VOUT + mbase) = stv; \
  }
  FC_STORE(acc0, 0) FC_STORE(acc1, 1) FC_STORE(acc2, 2) FC_STORE(acc3, 3)
#undef FC_STORE
}

extern "C" void kernel_launch(void* const* d_in, const int* in_sizes, int n_in,
                              void* d_out, int out_size, void* d_ws, size_t ws_size,
                              hipStream_t stream) {
  const int*   x      = (const int*)  d_in[0];
  const float* enc    = (const float*)d_in[1];
  const float* hidden = (const float*)d_in[2];
  const float* cell   = (const float*)d_in[3];
  const float* embt   = (const float*)d_in[4];
  const float* eW     = (const float*)d_in[5];
  const float* eb     = (const float*)d_in[6];
  const float* W_ih   = (const float*)d_in[7];
  const float* W_hh   = (const float*)d_in[8];
  const float* b_ih   = (const float*)d_in[9];
  const float* b_hh   = (const float*)d_in[10];
  const float* fc_W   = (const float*)d_in[11];
  const float* fc_b   = (const float*)d_in[12];

  float* out   = (float*)d_out;
  float* preds = out;                              // 64*32000
  float* out_h = out + (size_t)BATCH*VOUT;         // 64*1024
  float* out_c = out_h + BATCH*HDIM;               // 64*1024
  float* ws    = (float*)d_ws;
  unsigned short* rnnB = (unsigned short*)(ws + WS_RNNB);
  unsigned short* hB   = (unsigned short*)(ws + WS_HB16);

  k_attn<<<dim3(16, 64), 256, 0, stream>>>(enc, eW, eb, hidden, ws + WS_MS, ws + WS_CTX);
  k_combine<<<dim3(14, 64), 256, 0, stream>>>(ws + WS_MS, ws + WS_CTX, hidden, embt, x, rnnB);
  k_gates<<<512, 256, 0, stream>>>(rnnB, W_ih, W_hh, ws + WS_GP);
  k_lstm<<<256, 256, 0, stream>>>(ws + WS_GP, b_ih, b_hh, cell, out_h, out_c, hB);
  k_fc<<<500, 256, 0, stream>>>(hB, fc_W, fc_b, preds);
}

// Round 23
// 137.789 us; speedup vs baseline: 1.0359x; 1.0359x over previous
//
#include <hip/hip_runtime.h>

#define S_LEN 512
#define BATCH 64
#define HDIM  1024
#define TWOH  2048
#define EMB   512
#define KDIM  2560      // 2H + EMB
#define KTOT  3584      // 2H + EMB + H
#define VOUT  32000

// ws layout (float offsets)
#define WS_MS    64
#define WS_CTX   2112                        // f32 [64][16][2048] = 2,097,152 floats
#define WS_GP    WS_CTX                      // gate partials [8][4096][64] f32 — aliases dead ctx
#define WS_RNNB  (WS_CTX + 64*16*2048)       // bf16 [64][3584] = 114,688 floats
#define WS_HB16  (WS_RNNB + 114688)          // bf16 [64][1024] = 32,768 floats

typedef __attribute__((ext_vector_type(8))) short bf16x8;
typedef __attribute__((ext_vector_type(4))) float f32x4;

__device__ __forceinline__ float sigmoidf_(float x) { return 1.f/(1.f+__expf(-x)); }

// RNE float -> bf16 (finite inputs)
__device__ __forceinline__ unsigned short f2bf(float f) {
  union { float f; unsigned u; } v; v.f = f;
  return (unsigned short)((v.u + 0x7fffu + ((v.u >> 16) & 1u)) >> 16);
}

// K1 v3: single-pass online-softmax context, row-pipelined, hb inline.
__global__ __launch_bounds__(256) void k_attn(const float* __restrict__ enc,
                                              const float* __restrict__ eW,
                                              const float* __restrict__ eb,
                                              const float* __restrict__ hidden,
                                              float* __restrict__ ws_ms,
                                              float* __restrict__ ws_ctx) {
  __shared__ float lds_ms[4][2];
  __shared__ float lds_ctx[4][2048];
  const int lane  = threadIdx.x & 63;
  const int wave  = threadIdx.x >> 6;
  const int chunk = blockIdx.x;   // 0..15
  const int b     = blockIdx.y;   // 0..63

  float hba = 0.f;
  for (int k = lane; k < HDIM; k += 64) hba += hidden[b*HDIM + k] * eW[k];
#pragma unroll
  for (int st = 32; st >= 1; st >>= 1) hba += __shfl_xor(hba, st, 64);
  const float hb = hba + eb[0];

  float4 w4[8];
#pragma unroll
  for (int k = 0; k < 8; ++k)
    w4[k] = *reinterpret_cast<const float4*>(eW + HDIM + 4*lane + 256*k);

  const int s0 = chunk*32 + wave*8;
  const float* base = enc + ((size_t)(s0*BATCH + b))*TWOH + 4*lane;

  float m = 0.f, ssum = 0.f;      // relu => e >= 0
  float4 ctx[8];
#pragma unroll
  for (int k = 0; k < 8; ++k) ctx[k] = make_float4(0.f, 0.f, 0.f, 0.f);

  float4 va[8], vb[8];
#pragma unroll
  for (int k = 0; k < 8; ++k) va[k] = *reinterpret_cast<const float4*>(base + 256*k);

#define ATTN_STEP(VCUR, VNXT, I)                                              \
  {                                                                           \
    if ((I) < 7) {                                                            \
      const float* pn = base + (size_t)((I)+1)*BATCH*TWOH;                    \
      _Pragma("unroll")                                                       \
      for (int k = 0; k < 8; ++k)                                             \
        VNXT[k] = *reinterpret_cast<const float4*>(pn + 256*k);               \
    }                                                                         \
    float a = 0.f;                                                            \
    _Pragma("unroll")                                                         \
    for (int k = 0; k < 8; ++k)                                               \
      a += VCUR[k].x*w4[k].x + VCUR[k].y*w4[k].y +                            \
           VCUR[k].z*w4[k].z + VCUR[k].w*w4[k].w;                             \
    _Pragma("unroll")                                                         \
    for (int st = 1; st < 64; st <<= 1) a += __shfl_xor(a, st, 64);           \
    const float e = fmaxf(a + hb, 0.f);                                       \
    if (e > m) {                                                              \
      const float sc = __expf(m - e);                                         \
      ssum = ssum*sc + 1.f;                                                   \
      _Pragma("unroll")                                                       \
      for (int k = 0; k < 8; ++k) {                                           \
        ctx[k].x = fmaf(ctx[k].x, sc, VCUR[k].x);                             \
        ctx[k].y = fmaf(ctx[k].y, sc, VCUR[k].y);                             \
        ctx[k].z = fmaf(ctx[k].z, sc, VCUR[k].z);                             \
        ctx[k].w = fmaf(ctx[k].w, sc, VCUR[k].w);                             \
      }                                                                       \
      m = e;                                                                  \
    } else {                                                                  \
      const float pw = __expf(e - m);                                         \
      ssum += pw;                                                             \
      _Pragma("unroll")                                                       \
      for (int k = 0; k < 8; ++k) {                                           \
        ctx[k].x = fmaf(pw, VCUR[k].x, ctx[k].x);                             \
        ctx[k].y = fmaf(pw, VCUR[k].y, ctx[k].y);                             \
        ctx[k].z = fmaf(pw, VCUR[k].z, ctx[k].z);                             \
        ctx[k].w = fmaf(pw, VCUR[k].w, ctx[k].w);                             \
      }                                                                       \
    }                                                                         \
  }

  ATTN_STEP(va, vb, 0)
  ATTN_STEP(vb, va, 1)
  ATTN_STEP(va, vb, 2)
  ATTN_STEP(vb, va, 3)
  ATTN_STEP(va, vb, 4)
  ATTN_STEP(vb, va, 5)
  ATTN_STEP(va, vb, 6)
  ATTN_STEP(vb, va, 7)
#undef ATTN_STEP

  if (lane == 0) { lds_ms[wave][0] = m; lds_ms[wave][1] = ssum; }
  __syncthreads();
  const float M = fmaxf(fmaxf(lds_ms[0][0], lds_ms[1][0]),
                        fmaxf(lds_ms[2][0], lds_ms[3][0]));
  const float wsc = __expf(m - M);
  float ssum_c = 0.f;
#pragma unroll
  for (int w = 0; w < 4; ++w) ssum_c += __expf(lds_ms[w][0] - M) * lds_ms[w][1];
#pragma unroll
  for (int k = 0; k < 8; ++k) {
    float4 c = ctx[k];
    c.x *= wsc; c.y *= wsc; c.z *= wsc; c.w *= wsc;
    *reinterpret_cast<float4*>(&lds_ctx[wave][4*lane + 256*k]) = c;
  }
  __syncthreads();
  float* outp = ws_ctx + ((size_t)b*16 + chunk)*TWOH;
  for (int d = threadIdx.x; d < TWOH; d += 256)
    outp[d] = lds_ctx[0][d] + lds_ctx[1][d] + lds_ctx[2][d] + lds_ctx[3][d];
  if (threadIdx.x == 0) {
    ws_ms[((size_t)b*16 + chunk)*2]     = M;
    ws_ms[((size_t)b*16 + chunk)*2 + 1] = ssum_c;
  }
}

// K2 v4: parallel combine. Grid (14 kchunks x 64 b), 1 thread = 1 output elem.
__global__ __launch_bounds__(256) void k_combine(const float* __restrict__ ws_ms,
                                                 const float* __restrict__ ws_ctx,
                                                 const float* __restrict__ hidden,
                                                 const float* __restrict__ emb_table,
                                                 const int* __restrict__ x,
                                                 unsigned short* __restrict__ rnnB) {
  const int b = blockIdx.y;
  const int k = blockIdx.x*256 + threadIdx.x;   // 0..3583
  unsigned short* rb = rnnB + (size_t)b*KTOT;

  if (k < TWOH) {
    float mc[16], sc[16];
#pragma unroll
    for (int c = 0; c < 16; ++c) {
      mc[c] = ws_ms[(b*16 + c)*2];
      sc[c] = ws_ms[(b*16 + c)*2 + 1];
    }
    float M = mc[0];
#pragma unroll
    for (int c = 1; c < 16; ++c) M = fmaxf(M, mc[c]);
    float wc[16], Ssum = 0.f;
#pragma unroll
    for (int c = 0; c < 16; ++c) { wc[c] = __expf(mc[c] - M); Ssum += wc[c]*sc[c]; }
    const float inv = 1.f / Ssum;
    float a = 0.f;
#pragma unroll
    for (int c = 0; c < 16; ++c) a += wc[c] * ws_ctx[((size_t)b*16 + c)*TWOH + k];
    rb[k] = f2bf(a * inv);
  } else if (k < KDIM) {
    const int xb = x[b];
    rb[k] = f2bf(emb_table[(size_t)xb*EMB + (k - TWOH)]);
  } else {
    rb[k] = f2bf(hidden[b*HDIM + (k - KDIM)]);
  }
}

// K3 v8 (R21 best): LDS-staged MFMA gate GEMM. Block = 64 gate rows x 64
// batch, 4 waves; split-K=8. Row-contiguous staging + XOR-swizzled
// double-buffered LDS, 1-deep prefetch.
__global__ __launch_bounds__(256) void k_gates(const unsigned short* __restrict__ rnnB,
                                               const float* __restrict__ W_ih,
                                               const float* __restrict__ W_hh,
                                               float* __restrict__ ws_gp) {
  __shared__ unsigned short lds_a[2][64*64];   // 2 x 8KB
  const int tid  = threadIdx.x;
  const int lane = tid & 63;
  const int wave = tid >> 6;
  const int part = blockIdx.x & 7;     // k-part: 448 each
  const int rg   = blockIdx.x >> 3;    // 0..63
  const int j0   = rg*64;              // block's first gate row
  const int mlo  = lane & 15;
  const int kg   = lane >> 4;
  const int srow = tid >> 4;           // staging row 0..15 (+jj*16)
  const int scol = (tid & 15) * 4;     // staging col (floats)

  const unsigned short* rp0 = rnnB + (size_t)mlo*KTOT;

  f32x4 acc0 = {0.f,0.f,0.f,0.f}, acc1 = acc0, acc2 = acc0, acc3 = acc0;
  float4 st[4];

#define G_GLOAD(C)                                                            \
  {                                                                           \
    const int kb = part*448 + (C)*64;                                         \
    _Pragma("unroll")                                                         \
    for (int jj = 0; jj < 4; ++jj) {                                          \
      const int r = j0 + srow + jj*16;                                        \
      const float* wrow = (kb < KDIM)                                         \
          ? (W_ih + (size_t)r*KDIM + kb + scol)                               \
          : (W_hh + (size_t)r*HDIM + (kb - KDIM) + scol);                     \
      st[jj] = *reinterpret_cast<const float4*>(wrow);                        \
    }                                                                         \
  }

#define G_SWRITE(BUF)                                                         \
  _Pragma("unroll")                                                           \
  for (int jj = 0; jj < 4; ++jj) {                                            \
    const int r = srow + jj*16;                                               \
    unsigned short tmp[4];                                                    \
    tmp[0] = f2bf(st[jj].x); tmp[1] = f2bf(st[jj].y);                         \
    tmp[2] = f2bf(st[jj].z); tmp[3] = f2bf(st[jj].w);                         \
    const int boff = r*128 + ((scol*2) ^ ((r & 7) << 4));                     \
    *reinterpret_cast<uint2*>(reinterpret_cast<char*>(lds_a[BUF]) + boff) =   \
        *reinterpret_cast<const uint2*>(tmp);                                 \
  }

  G_GLOAD(0)
  G_SWRITE(0)
  __syncthreads();

  int cur = 0;
  const int arow = wave*16 + mlo;
  const int abase = arow*128;
  const int asw  = (arow & 7) << 4;

  for (int c = 0; c < 7; ++c) {
    if (c < 6) G_GLOAD(c+1)

    const bf16x8 af0 = *reinterpret_cast<const bf16x8*>(
        reinterpret_cast<const char*>(lds_a[cur]) + abase + ((kg*16) ^ asw));
    const bf16x8 af1 = *reinterpret_cast<const bf16x8*>(
        reinterpret_cast<const char*>(lds_a[cur]) + abase + ((64 + kg*16) ^ asw));

    const size_t K0 = (size_t)part*448 + c*64 + kg*8;
    const bf16x8 b00 = *reinterpret_cast<const bf16x8*>(rp0 + K0);
    const bf16x8 b10 = *reinterpret_cast<const bf16x8*>(rp0 + 16*KTOT + K0);
    const bf16x8 b20 = *reinterpret_cast<const bf16x8*>(rp0 + 32*KTOT + K0);
    const bf16x8 b30 = *reinterpret_cast<const bf16x8*>(rp0 + 48*KTOT + K0);
    const bf16x8 b01 = *reinterpret_cast<const bf16x8*>(rp0 + K0 + 32);
    const bf16x8 b11 = *reinterpret_cast<const bf16x8*>(rp0 + 16*KTOT + K0 + 32);
    const bf16x8 b21 = *reinterpret_cast<const bf16x8*>(rp0 + 32*KTOT + K0 + 32);
    const bf16x8 b31 = *reinterpret_cast<const bf16x8*>(rp0 + 48*KTOT + K0 + 32);

    acc0 = __builtin_amdgcn_mfma_f32_16x16x32_bf16(af0, b00, acc0, 0, 0, 0);
    acc1 = __builtin_amdgcn_mfma_f32_16x16x32_bf16(af0, b10, acc1, 0, 0, 0);
    acc2 = __builtin_amdgcn_mfma_f32_16x16x32_bf16(af0, b20, acc2, 0, 0, 0);
    acc3 = __builtin_amdgcn_mfma_f32_16x16x32_bf16(af0, b30, acc3, 0, 0, 0);
    acc0 = __builtin_amdgcn_mfma_f32_16x16x32_bf16(af1, b01, acc0, 0, 0, 0);
    acc1 = __builtin_amdgcn_mfma_f32_16x16x32_bf16(af1, b11, acc1, 0, 0, 0);
    acc2 = __builtin_amdgcn_mfma_f32_16x16x32_bf16(af1, b21, acc2, 0, 0, 0);
    acc3 = __builtin_amdgcn_mfma_f32_16x16x32_bf16(af1, b31, acc3, 0, 0, 0);

    if (c < 6) G_SWRITE(cur ^ 1)
    __syncthreads();
    cur ^= 1;
  }
#undef G_GLOAD
#undef G_SWRITE

  const int mbase = j0 + wave*16 + kg*4;
#define G_ST(ACC, N)                                                          \
  {                                                                           \
    _Pragma("unroll")                                                         \
    for (int jj = 0; jj < 4; ++jj)                                            \
      ws_gp[((size_t)part*4096 + mbase + jj)*64 + ((N)*16 + mlo)] = ACC[jj];  \
  }
  G_ST(acc0, 0) G_ST(acc1, 1) G_ST(acc2, 2) G_ST(acc3, 3)
#undef G_ST
}

// K3b: sum 8 partials + biases, LSTM pointwise; emit h as f32 outs + bf16 hB.
__global__ __launch_bounds__(256) void k_lstm(const float* __restrict__ ws_gp,
                                              const float* __restrict__ b_ih,
                                              const float* __restrict__ b_hh,
                                              const float* __restrict__ cell,
                                              float* __restrict__ out_h,
                                              float* __restrict__ out_c,
                                              unsigned short* __restrict__ hB) {
  const int id = blockIdx.x*256 + threadIdx.x;  // 65536
  const int h = id >> 6, b = id & 63;
  float g[4];
#pragma unroll
  for (int gg = 0; gg < 4; ++gg) {
    const int j = gg*1024 + h;
    float v = b_ih[j] + b_hh[j];
#pragma unroll
    for (int p = 0; p < 8; ++p) v += ws_gp[((size_t)p*4096 + j)*64 + b];
    g[gg] = v;
  }
  const float iv = sigmoidf_(g[0]);
  const float fv = sigmoidf_(g[1]);
  const float gv = tanhf(g[2]);
  const float ov = sigmoidf_(g[3]);
  const float cold = cell[b*HDIM + h];
  const float cn = fmaf(fv, cold, iv*gv);
  const float hn = ov * tanhf(cn);
  out_h[b*HDIM + h] = hn;
  out_c[b*HDIM + h] = cn;
  hB[(size_t)b*HDIM + h] = f2bf(hn);
}

// K4 v12 (R20/R21 best): LDS-staged MFMA fc GEMM, 1-deep prefetch.
__global__ __launch_bounds__(256) void k_fc(const unsigned short* __restrict__ hB,
                                            const float* __restrict__ fc_W,
                                            const float* __restrict__ fc_b,
                                            float* __restrict__ preds) {
  __shared__ unsigned short lds_a[2][64*64];   // 2 x 8KB
  const int tid  = threadIdx.x;
  const int lane = tid & 63;
  const int wave = tid >> 6;
  const int row0b = blockIdx.x * 64;           // grid 500 -> 32000 rows
  const int mlo  = lane & 15;
  const int kg   = lane >> 4;
  const int srow = tid >> 4;                   // staging row 0..15 (+j*16)
  const int scol = (tid & 15) * 4;             // staging col (floats)

  const unsigned short* hp = hB + (size_t)mlo*HDIM + kg*8;

  f32x4 acc0 = {0.f,0.f,0.f,0.f}, acc1 = acc0, acc2 = acc0, acc3 = acc0;
  float4 st[4];

#define FC_GLOAD(C)                                                           \
  _Pragma("unroll")                                                           \
  for (int jj = 0; jj < 4; ++jj)                                              \
    st[jj] = *reinterpret_cast<const float4*>(                                \
        fc_W + (size_t)(row0b + srow + jj*16)*HDIM + (C)*64 + scol);

#define FC_SWRITE(BUF)                                                        \
  _Pragma("unroll")                                                           \
  for (int jj = 0; jj < 4; ++jj) {                                            \
    const int r = srow + jj*16;                                               \
    unsigned short tmp[4];                                                    \
    tmp[0] = f2bf(st[jj].x); tmp[1] = f2bf(st[jj].y);                         \
    tmp[2] = f2bf(st[jj].z); tmp[3] = f2bf(st[jj].w);                         \
    const int boff = r*128 + ((scol*2) ^ ((r & 7) << 4));                     \
    *reinterpret_cast<uint2*>(reinterpret_cast<char*>(lds_a[BUF]) + boff) =   \
        *reinterpret_cast<const uint2*>(tmp);                                 \
  }

  FC_GLOAD(0)
  FC_SWRITE(0)
  __syncthreads();

  int cur = 0;
  const int arow = wave*16 + mlo;
  const int abase = arow*128;
  const int asw  = (arow & 7) << 4;

  for (int c = 0; c < 16; ++c) {
    if (c < 15) FC_GLOAD(c+1)

    const bf16x8 af0 = *reinterpret_cast<const bf16x8*>(
        reinterpret_cast<const char*>(lds_a[cur]) + abase + ((kg*16) ^ asw));
    const bf16x8 af1 = *reinterpret_cast<const bf16x8*>(
        reinterpret_cast<const char*>(lds_a[cur]) + abase + ((64 + kg*16) ^ asw));

    const int K0 = c*64;
    const bf16x8 b00 = *reinterpret_cast<const bf16x8*>(hp + K0);
    const bf16x8 b10 = *reinterpret_cast<const bf16x8*>(hp + 16*HDIM + K0);
    const bf16x8 b20 = *reinterpret_cast<const bf16x8*>(hp + 32*HDIM + K0);
    const bf16x8 b30 = *reinterpret_cast<const bf16x8*>(hp + 48*HDIM + K0);
    const bf16x8 b01 = *reinterpret_cast<const bf16x8*>(hp + K0 + 32);
    const bf16x8 b11 = *reinterpret_cast<const bf16x8*>(hp + 16*HDIM + K0 + 32);
    const bf16x8 b21 = *reinterpret_cast<const bf16x8*>(hp + 32*HDIM + K0 + 32);
    const bf16x8 b31 = *reinterpret_cast<const bf16x8*>(hp + 48*HDIM + K0 + 32);

    acc0 = __builtin_amdgcn_mfma_f32_16x16x32_bf16(af0, b00, acc0, 0, 0, 0);
    acc1 = __builtin_amdgcn_mfma_f32_16x16x32_bf16(af0, b10, acc1, 0, 0, 0);
    acc2 = __builtin_amdgcn_mfma_f32_16x16x32_bf16(af0, b20, acc2, 0, 0, 0);
    acc3 = __builtin_amdgcn_mfma_f32_16x16x32_bf16(af0, b30, acc3, 0, 0, 0);
    acc0 = __builtin_amdgcn_mfma_f32_16x16x32_bf16(af1, b01, acc0, 0, 0, 0);
    acc1 = __builtin_amdgcn_mfma_f32_16x16x32_bf16(af1, b11, acc1, 0, 0, 0);
    acc2 = __builtin_amdgcn_mfma_f32_16x16x32_bf16(af1, b21, acc2, 0, 0, 0);
    acc3 = __builtin_amdgcn_mfma_f32_16x16x32_bf16(af1, b31, acc3, 0, 0, 0);

    if (c < 15) FC_SWRITE(cur ^ 1)
    __syncthreads();
    cur ^= 1;
  }
#undef FC_GLOAD
#undef FC_SWRITE

  const int mbase = row0b + wave*16 + kg*4;
  const float4 bias = make_float4(fc_b[mbase], fc_b[mbase+1],
                                  fc_b[mbase+2], fc_b[mbase+3]);
#define FC_STORE(ACC, N)                                                      \
  {                                                                           \
    float4 stv = make_float4(ACC[0] + bias.x, ACC[1] + bias.y,                \
                             ACC[2] + bias.z, ACC[3] + bias.w);               \
    *reinterpret_cast<float4*>(preds + (size_t)((N)*16 + mlo)*VOUT + mbase) = stv; \
  }
  FC_STORE(acc0, 0) FC_STORE(acc1, 1) FC_STORE(acc2, 2) FC_STORE(acc3, 3)
#undef FC_STORE
}

extern "C" void kernel_launch(void* const* d_in, const int* in_sizes, int n_in,
                              void* d_out, int out_size, void* d_ws, size_t ws_size,
                              hipStream_t stream) {
  const int*   x      = (const int*)  d_in[0];
  const float* enc    = (const float*)d_in[1];
  const float* hidden = (const float*)d_in[2];
  const float* cell   = (const float*)d_in[3];
  const float* embt   = (const float*)d_in[4];
  const float* eW     = (const float*)d_in[5];
  const float* eb     = (const float*)d_in[6];
  const float* W_ih   = (const float*)d_in[7];
  const float* W_hh   = (const float*)d_in[8];
  const float* b_ih   = (const float*)d_in[9];
  const float* b_hh   = (const float*)d_in[10];
  const float* fc_W   = (const float*)d_in[11];
  const float* fc_b   = (const float*)d_in[12];

  float* out   = (float*)d_out;
  float* preds = out;                              // 64*32000
  float* out_h = out + (size_t)BATCH*VOUT;         // 64*1024
  float* out_c = out_h + BATCH*HDIM;               // 64*1024
  float* ws    = (float*)d_ws;
  unsigned short* rnnB = (unsigned short*)(ws + WS_RNNB);
  unsigned short* hB   = (unsigned short*)(ws + WS_HB16);

  k_attn<<<dim3(16, 64), 256, 0, stream>>>(enc, eW, eb, hidden, ws + WS_MS, ws + WS_CTX);
  k_combine<<<dim3(14, 64), 256, 0, stream>>>(ws + WS_MS, ws + WS_CTX, hidden, embt, x, rnnB);
  k_gates<<<512, 256, 0, stream>>>(rnnB, W_ih, W_hh, ws + WS_GP);
  k_lstm<<<256, 256, 0, stream>>>(ws + WS_GP, b_ih, b_hh, cell, out_h, out_c, hB);
  k_fc<<<500, 256, 0, stream>>>(hB, fc_W, fc_b, preds);
}

// Round 24
// 136.609 us; speedup vs baseline: 1.0448x; 1.0086x over previous
//
#include <hip/hip_runtime.h>

#define S_LEN 512
#define BATCH 64
#define HDIM  1024
#define TWOH  2048
#define EMB   512
#define KDIM  2560      // 2H + EMB
#define KTOT  3584      // 2H + EMB + H
#define VOUT  32000

// ws layout (float offsets)
#define WS_MS    64
#define WS_CTX   2112                        // f32 [64][16][2048] = 2,097,152 floats
#define WS_GP    WS_CTX                      // gate partials [8][4096][64] f32 — aliases dead ctx
#define WS_RNNB  (WS_CTX + 64*16*2048)       // bf16 [64][3584] = 114,688 floats
#define WS_HB16  (WS_RNNB + 114688)          // bf16 [64][1024] = 32,768 floats

typedef __attribute__((ext_vector_type(8))) short bf16x8;
typedef __attribute__((ext_vector_type(4))) float f32x4;

__device__ __forceinline__ float sigmoidf_(float x) { return 1.f/(1.f+__expf(-x)); }

// RNE float -> bf16 (finite inputs)
__device__ __forceinline__ unsigned short f2bf(float f) {
  union { float f; unsigned u; } v; v.f = f;
  return (unsigned short)((v.u + 0x7fffu + ((v.u >> 16) & 1u)) >> 16);
}

// K1 v3: single-pass online-softmax context, row-pipelined, hb inline.
__global__ __launch_bounds__(256) void k_attn(const float* __restrict__ enc,
                                              const float* __restrict__ eW,
                                              const float* __restrict__ eb,
                                              const float* __restrict__ hidden,
                                              float* __restrict__ ws_ms,
                                              float* __restrict__ ws_ctx) {
  __shared__ float lds_ms[4][2];
  __shared__ float lds_ctx[4][2048];
  const int lane  = threadIdx.x & 63;
  const int wave  = threadIdx.x >> 6;
  const int chunk = blockIdx.x;   // 0..15
  const int b     = blockIdx.y;   // 0..63

  float hba = 0.f;
  for (int k = lane; k < HDIM; k += 64) hba += hidden[b*HDIM + k] * eW[k];
#pragma unroll
  for (int st = 32; st >= 1; st >>= 1) hba += __shfl_xor(hba, st, 64);
  const float hb = hba + eb[0];

  float4 w4[8];
#pragma unroll
  for (int k = 0; k < 8; ++k)
    w4[k] = *reinterpret_cast<const float4*>(eW + HDIM + 4*lane + 256*k);

  const int s0 = chunk*32 + wave*8;
  const float* base = enc + ((size_t)(s0*BATCH + b))*TWOH + 4*lane;

  float m = 0.f, ssum = 0.f;      // relu => e >= 0
  float4 ctx[8];
#pragma unroll
  for (int k = 0; k < 8; ++k) ctx[k] = make_float4(0.f, 0.f, 0.f, 0.f);

  float4 va[8], vb[8];
#pragma unroll
  for (int k = 0; k < 8; ++k) va[k] = *reinterpret_cast<const float4*>(base + 256*k);

#define ATTN_STEP(VCUR, VNXT, I)                                              \
  {                                                                           \
    if ((I) < 7) {                                                            \
      const float* pn = base + (size_t)((I)+1)*BATCH*TWOH;                    \
      _Pragma("unroll")                                                       \
      for (int k = 0; k < 8; ++k)                                             \
        VNXT[k] = *reinterpret_cast<const float4*>(pn + 256*k);               \
    }                                                                         \
    float a = 0.f;                                                            \
    _Pragma("unroll")                                                         \
    for (int k = 0; k < 8; ++k)                                               \
      a += VCUR[k].x*w4[k].x + VCUR[k].y*w4[k].y +                            \
           VCUR[k].z*w4[k].z + VCUR[k].w*w4[k].w;                             \
    _Pragma("unroll")                                                         \
    for (int st = 1; st < 64; st <<= 1) a += __shfl_xor(a, st, 64);           \
    const float e = fmaxf(a + hb, 0.f);                                       \
    if (e > m) {                                                              \
      const float sc = __expf(m - e);                                         \
      ssum = ssum*sc + 1.f;                                                   \
      _Pragma("unroll")                                                       \
      for (int k = 0; k < 8; ++k) {                                           \
        ctx[k].x = fmaf(ctx[k].x, sc, VCUR[k].x);                             \
        ctx[k].y = fmaf(ctx[k].y, sc, VCUR[k].y);                             \
        ctx[k].z = fmaf(ctx[k].z, sc, VCUR[k].z);                             \
        ctx[k].w = fmaf(ctx[k].w, sc, VCUR[k].w);                             \
      }                                                                       \
      m = e;                                                                  \
    } else {                                                                  \
      const float pw = __expf(e - m);                                         \
      ssum += pw;                                                             \
      _Pragma("unroll")                                                       \
      for (int k = 0; k < 8; ++k) {                                           \
        ctx[k].x = fmaf(pw, VCUR[k].x, ctx[k].x);                             \
        ctx[k].y = fmaf(pw, VCUR[k].y, ctx[k].y);                             \
        ctx[k].z = fmaf(pw, VCUR[k].z, ctx[k].z);                             \
        ctx[k].w = fmaf(pw, VCUR[k].w, ctx[k].w);                             \
      }                                                                       \
    }                                                                         \
  }

  ATTN_STEP(va, vb, 0)
  ATTN_STEP(vb, va, 1)
  ATTN_STEP(va, vb, 2)
  ATTN_STEP(vb, va, 3)
  ATTN_STEP(va, vb, 4)
  ATTN_STEP(vb, va, 5)
  ATTN_STEP(va, vb, 6)
  ATTN_STEP(vb, va, 7)
#undef ATTN_STEP

  if (lane == 0) { lds_ms[wave][0] = m; lds_ms[wave][1] = ssum; }
  __syncthreads();
  const float M = fmaxf(fmaxf(lds_ms[0][0], lds_ms[1][0]),
                        fmaxf(lds_ms[2][0], lds_ms[3][0]));
  const float wsc = __expf(m - M);
  float ssum_c = 0.f;
#pragma unroll
  for (int w = 0; w < 4; ++w) ssum_c += __expf(lds_ms[w][0] - M) * lds_ms[w][1];
#pragma unroll
  for (int k = 0; k < 8; ++k) {
    float4 c = ctx[k];
    c.x *= wsc; c.y *= wsc; c.z *= wsc; c.w *= wsc;
    *reinterpret_cast<float4*>(&lds_ctx[wave][4*lane + 256*k]) = c;
  }
  __syncthreads();
  float* outp = ws_ctx + ((size_t)b*16 + chunk)*TWOH;
  for (int d = threadIdx.x; d < TWOH; d += 256)
    outp[d] = lds_ctx[0][d] + lds_ctx[1][d] + lds_ctx[2][d] + lds_ctx[3][d];
  if (threadIdx.x == 0) {
    ws_ms[((size_t)b*16 + chunk)*2]     = M;
    ws_ms[((size_t)b*16 + chunk)*2 + 1] = ssum_c;
  }
}

// K2 v4: parallel combine. Grid (14 kchunks x 64 b), 1 thread = 1 output elem.
__global__ __launch_bounds__(256) void k_combine(const float* __restrict__ ws_ms,
                                                 const float* __restrict__ ws_ctx,
                                                 const float* __restrict__ hidden,
                                                 const float* __restrict__ emb_table,
                                                 const int* __restrict__ x,
                                                 unsigned short* __restrict__ rnnB) {
  const int b = blockIdx.y;
  const int k = blockIdx.x*256 + threadIdx.x;   // 0..3583
  unsigned short* rb = rnnB + (size_t)b*KTOT;

  if (k < TWOH) {
    float mc[16], sc[16];
#pragma unroll
    for (int c = 0; c < 16; ++c) {
      mc[c] = ws_ms[(b*16 + c)*2];
      sc[c] = ws_ms[(b*16 + c)*2 + 1];
    }
    float M = mc[0];
#pragma unroll
    for (int c = 1; c < 16; ++c) M = fmaxf(M, mc[c]);
    float wc[16], Ssum = 0.f;
#pragma unroll
    for (int c = 0; c < 16; ++c) { wc[c] = __expf(mc[c] - M); Ssum += wc[c]*sc[c]; }
    const float inv = 1.f / Ssum;
    float a = 0.f;
#pragma unroll
    for (int c = 0; c < 16; ++c) a += wc[c] * ws_ctx[((size_t)b*16 + c)*TWOH + k];
    rb[k] = f2bf(a * inv);
  } else if (k < KDIM) {
    const int xb = x[b];
    rb[k] = f2bf(emb_table[(size_t)xb*EMB + (k - TWOH)]);
  } else {
    rb[k] = f2bf(hidden[b*HDIM + (k - KDIM)]);
  }
}

// K3 v8 (R21 best): LDS-staged MFMA gate GEMM. Block = 64 gate rows x 64
// batch, 4 waves; split-K=8. Row-contiguous staging + XOR-swizzled
// double-buffered LDS, 1-deep prefetch.
__global__ __launch_bounds__(256) void k_gates(const unsigned short* __restrict__ rnnB,
                                               const float* __restrict__ W_ih,
                                               const float* __restrict__ W_hh,
                                               float* __restrict__ ws_gp) {
  __shared__ unsigned short lds_a[2][64*64];   // 2 x 8KB
  const int tid  = threadIdx.x;
  const int lane = tid & 63;
  const int wave = tid >> 6;
  const int part = blockIdx.x & 7;     // k-part: 448 each
  const int rg   = blockIdx.x >> 3;    // 0..63
  const int j0   = rg*64;              // block's first gate row
  const int mlo  = lane & 15;
  const int kg   = lane >> 4;
  const int srow = tid >> 4;           // staging row 0..15 (+jj*16)
  const int scol = (tid & 15) * 4;     // staging col (floats)

  const unsigned short* rp0 = rnnB + (size_t)mlo*KTOT;

  f32x4 acc0 = {0.f,0.f,0.f,0.f}, acc1 = acc0, acc2 = acc0, acc3 = acc0;
  float4 st[4];

#define G_GLOAD(C)                                                            \
  {                                                                           \
    const int kb = part*448 + (C)*64;                                         \
    _Pragma("unroll")                                                         \
    for (int jj = 0; jj < 4; ++jj) {                                          \
      const int r = j0 + srow + jj*16;                                        \
      const float* wrow = (kb < KDIM)                                         \
          ? (W_ih + (size_t)r*KDIM + kb + scol)                               \
          : (W_hh + (size_t)r*HDIM + (kb - KDIM) + scol);                     \
      st[jj] = *reinterpret_cast<const float4*>(wrow);                        \
    }                                                                         \
  }

#define G_SWRITE(BUF)                                                         \
  _Pragma("unroll")                                                           \
  for (int jj = 0; jj < 4; ++jj) {                                            \
    const int r = srow + jj*16;                                               \
    unsigned short tmp[4];                                                    \
    tmp[0] = f2bf(st[jj].x); tmp[1] = f2bf(st[jj].y);                         \
    tmp[2] = f2bf(st[jj].z); tmp[3] = f2bf(st[jj].w);                         \
    const int boff = r*128 + ((scol*2) ^ ((r & 7) << 4));                     \
    *reinterpret_cast<uint2*>(reinterpret_cast<char*>(lds_a[BUF]) + boff) =   \
        *reinterpret_cast<const uint2*>(tmp);                                 \
  }

  G_GLOAD(0)
  G_SWRITE(0)
  __syncthreads();

  int cur = 0;
  const int arow = wave*16 + mlo;
  const int abase = arow*128;
  const int asw  = (arow & 7) << 4;

  for (int c = 0; c < 7; ++c) {
    if (c < 6) G_GLOAD(c+1)

    const bf16x8 af0 = *reinterpret_cast<const bf16x8*>(
        reinterpret_cast<const char*>(lds_a[cur]) + abase + ((kg*16) ^ asw));
    const bf16x8 af1 = *reinterpret_cast<const bf16x8*>(
        reinterpret_cast<const char*>(lds_a[cur]) + abase + ((64 + kg*16) ^ asw));

    const size_t K0 = (size_t)part*448 + c*64 + kg*8;
    const bf16x8 b00 = *reinterpret_cast<const bf16x8*>(rp0 + K0);
    const bf16x8 b10 = *reinterpret_cast<const bf16x8*>(rp0 + 16*KTOT + K0);
    const bf16x8 b20 = *reinterpret_cast<const bf16x8*>(rp0 + 32*KTOT + K0);
    const bf16x8 b30 = *reinterpret_cast<const bf16x8*>(rp0 + 48*KTOT + K0);
    const bf16x8 b01 = *reinterpret_cast<const bf16x8*>(rp0 + K0 + 32);
    const bf16x8 b11 = *reinterpret_cast<const bf16x8*>(rp0 + 16*KTOT + K0 + 32);
    const bf16x8 b21 = *reinterpret_cast<const bf16x8*>(rp0 + 32*KTOT + K0 + 32);
    const bf16x8 b31 = *reinterpret_cast<const bf16x8*>(rp0 + 48*KTOT + K0 + 32);

    acc0 = __builtin_amdgcn_mfma_f32_16x16x32_bf16(af0, b00, acc0, 0, 0, 0);
    acc1 = __builtin_amdgcn_mfma_f32_16x16x32_bf16(af0, b10, acc1, 0, 0, 0);
    acc2 = __builtin_amdgcn_mfma_f32_16x16x32_bf16(af0, b20, acc2, 0, 0, 0);
    acc3 = __builtin_amdgcn_mfma_f32_16x16x32_bf16(af0, b30, acc3, 0, 0, 0);
    acc0 = __builtin_amdgcn_mfma_f32_16x16x32_bf16(af1, b01, acc0, 0, 0, 0);
    acc1 = __builtin_amdgcn_mfma_f32_16x16x32_bf16(af1, b11, acc1, 0, 0, 0);
    acc2 = __builtin_amdgcn_mfma_f32_16x16x32_bf16(af1, b21, acc2, 0, 0, 0);
    acc3 = __builtin_amdgcn_mfma_f32_16x16x32_bf16(af1, b31, acc3, 0, 0, 0);

    if (c < 6) G_SWRITE(cur ^ 1)
    __syncthreads();
    cur ^= 1;
  }
#undef G_GLOAD
#undef G_SWRITE

  const int mbase = j0 + wave*16 + kg*4;
#define G_ST(ACC, N)                                                          \
  {                                                                           \
    _Pragma("unroll")                                                         \
    for (int jj = 0; jj < 4; ++jj)                                            \
      ws_gp[((size_t)part*4096 + mbase + jj)*64 + ((N)*16 + mlo)] = ACC[jj];  \
  }
  G_ST(acc0, 0) G_ST(acc1, 1) G_ST(acc2, 2) G_ST(acc3, 3)
#undef G_ST
}

// K3b: sum 8 partials + biases, LSTM pointwise; emit h as f32 outs + bf16 hB.
__global__ __launch_bounds__(256) void k_lstm(const float* __restrict__ ws_gp,
                                              const float* __restrict__ b_ih,
                                              const float* __restrict__ b_hh,
                                              const float* __restrict__ cell,
                                              float* __restrict__ out_h,
                                              float* __restrict__ out_c,
                                              unsigned short* __restrict__ hB) {
  const int id = blockIdx.x*256 + threadIdx.x;  // 65536
  const int h = id >> 6, b = id & 63;
  float g[4];
#pragma unroll
  for (int gg = 0; gg < 4; ++gg) {
    const int j = gg*1024 + h;
    float v = b_ih[j] + b_hh[j];
#pragma unroll
    for (int p = 0; p < 8; ++p) v += ws_gp[((size_t)p*4096 + j)*64 + b];
    g[gg] = v;
  }
  const float iv = sigmoidf_(g[0]);
  const float fv = sigmoidf_(g[1]);
  const float gv = tanhf(g[2]);
  const float ov = sigmoidf_(g[3]);
  const float cold = cell[b*HDIM + h];
  const float cn = fmaf(fv, cold, iv*gv);
  const float hn = ov * tanhf(cn);
  out_h[b*HDIM + h] = hn;
  out_c[b*HDIM + h] = cn;
  hB[(size_t)b*HDIM + h] = f2bf(hn);
}

// K4 v14: LDS-staged MFMA fc GEMM, HALF-SIZE BLOCKS: 128 threads (2 waves),
// 32 rows/block, grid 1000. Same per-wave work/arithmetic as v12; smaller
// barrier domain + 2x independent blocks/CU for cross-block latency cover.
__global__ __launch_bounds__(128) void k_fc(const unsigned short* __restrict__ hB,
                                            const float* __restrict__ fc_W,
                                            const float* __restrict__ fc_b,
                                            float* __restrict__ preds) {
  __shared__ unsigned short lds_a[2][32*64];   // 2 x 4KB
  const int tid  = threadIdx.x;                // 0..127
  const int lane = tid & 63;
  const int wave = tid >> 6;                   // 0..1
  const int row0b = blockIdx.x * 32;           // grid 1000 -> 32000 rows
  const int mlo  = lane & 15;
  const int kg   = lane >> 4;
  const int srow = tid >> 4;                   // staging row 0..7 (+jj*8)
  const int scol = (tid & 15) * 4;             // staging col (floats)

  const unsigned short* hp = hB + (size_t)mlo*HDIM + kg*8;

  f32x4 acc0 = {0.f,0.f,0.f,0.f}, acc1 = acc0, acc2 = acc0, acc3 = acc0;
  float4 st[4];

#define FC_GLOAD(C)                                                           \
  _Pragma("unroll")                                                           \
  for (int jj = 0; jj < 4; ++jj)                                              \
    st[jj] = *reinterpret_cast<const float4*>(                                \
        fc_W + (size_t)(row0b + srow + jj*8)*HDIM + (C)*64 + scol);

#define FC_SWRITE(BUF)                                                        \
  _Pragma("unroll")                                                           \
  for (int jj = 0; jj < 4; ++jj) {                                            \
    const int r = srow + jj*8;                                                \
    unsigned short tmp[4];                                                    \
    tmp[0] = f2bf(st[jj].x); tmp[1] = f2bf(st[jj].y);                         \
    tmp[2] = f2bf(st[jj].z); tmp[3] = f2bf(st[jj].w);                         \
    const int boff = r*128 + ((scol*2) ^ ((r & 7) << 4));                     \
    *reinterpret_cast<uint2*>(reinterpret_cast<char*>(lds_a[BUF]) + boff) =   \
        *reinterpret_cast<const uint2*>(tmp);                                 \
  }

  FC_GLOAD(0)
  FC_SWRITE(0)
  __syncthreads();

  int cur = 0;
  const int arow = wave*16 + mlo;              // 0..31
  const int abase = arow*128;
  const int asw  = (arow & 7) << 4;

  for (int c = 0; c < 16; ++c) {
    if (c < 15) FC_GLOAD(c+1)

    const bf16x8 af0 = *reinterpret_cast<const bf16x8*>(
        reinterpret_cast<const char*>(lds_a[cur]) + abase + ((kg*16) ^ asw));
    const bf16x8 af1 = *reinterpret_cast<const bf16x8*>(
        reinterpret_cast<const char*>(lds_a[cur]) + abase + ((64 + kg*16) ^ asw));

    const int K0 = c*64;
    const bf16x8 b00 = *reinterpret_cast<const bf16x8*>(hp + K0);
    const bf16x8 b10 = *reinterpret_cast<const bf16x8*>(hp + 16*HDIM + K0);
    const bf16x8 b20 = *reinterpret_cast<const bf16x8*>(hp + 32*HDIM + K0);
    const bf16x8 b30 = *reinterpret_cast<const bf16x8*>(hp + 48*HDIM + K0);
    const bf16x8 b01 = *reinterpret_cast<const bf16x8*>(hp + K0 + 32);
    const bf16x8 b11 = *reinterpret_cast<const bf16x8*>(hp + 16*HDIM + K0 + 32);
    const bf16x8 b21 = *reinterpret_cast<const bf16x8*>(hp + 32*HDIM + K0 + 32);
    const bf16x8 b31 = *reinterpret_cast<const bf16x8*>(hp + 48*HDIM + K0 + 32);

    acc0 = __builtin_amdgcn_mfma_f32_16x16x32_bf16(af0, b00, acc0, 0, 0, 0);
    acc1 = __builtin_amdgcn_mfma_f32_16x16x32_bf16(af0, b10, acc1, 0, 0, 0);
    acc2 = __builtin_amdgcn_mfma_f32_16x16x32_bf16(af0, b20, acc2, 0, 0, 0);
    acc3 = __builtin_amdgcn_mfma_f32_16x16x32_bf16(af0, b30, acc3, 0, 0, 0);
    acc0 = __builtin_amdgcn_mfma_f32_16x16x32_bf16(af1, b01, acc0, 0, 0, 0);
    acc1 = __builtin_amdgcn_mfma_f32_16x16x32_bf16(af1, b11, acc1, 0, 0, 0);
    acc2 = __builtin_amdgcn_mfma_f32_16x16x32_bf16(af1, b21, acc2, 0, 0, 0);
    acc3 = __builtin_amdgcn_mfma_f32_16x16x32_bf16(af1, b31, acc3, 0, 0, 0);

    if (c < 15) FC_SWRITE(cur ^ 1)
    __syncthreads();
    cur ^= 1;
  }
#undef FC_GLOAD
#undef FC_SWRITE

  const int mbase = row0b + wave*16 + kg*4;
  const float4 bias = make_float4(fc_b[mbase], fc_b[mbase+1],
                                  fc_b[mbase+2], fc_b[mbase+3]);
#define FC_STORE(ACC, N)                                                      \
  {                                                                           \
    float4 stv = make_float4(ACC[0] + bias.x, ACC[1] + bias.y,                \
                             ACC[2] + bias.z, ACC[3] + bias.w);               \
    *reinterpret_cast<float4*>(preds + (size_t)((N)*16 + mlo)*VOUT + mbase) = stv; \
  }
  FC_STORE(acc0, 0) FC_STORE(acc1, 1) FC_STORE(acc2, 2) FC_STORE(acc3, 3)
#undef FC_STORE
}

extern "C" void kernel_launch(void* const* d_in, const int* in_sizes, int n_in,
                              void* d_out, int out_size, void* d_ws, size_t ws_size,
                              hipStream_t stream) {
  const int*   x      = (const int*)  d_in[0];
  const float* enc    = (const float*)d_in[1];
  const float* hidden = (const float*)d_in[2];
  const float* cell   = (const float*)d_in[3];
  const float* embt   = (const float*)d_in[4];
  const float* eW     = (const float*)d_in[5];
  const float* eb     = (const float*)d_in[6];
  const float* W_ih   = (const float*)d_in[7];
  const float* W_hh   = (const float*)d_in[8];
  const float* b_ih   = (const float*)d_in[9];
  const float* b_hh   = (const float*)d_in[10];
  const float* fc_W   = (const float*)d_in[11];
  const float* fc_b   = (const float*)d_in[12];

  float* out   = (float*)d_out;
  float* preds = out;                              // 64*32000
  float* out_h = out + (size_t)BATCH*VOUT;         // 64*1024
  float* out_c = out_h + BATCH*HDIM;               // 64*1024
  float* ws    = (float*)d_ws;
  unsigned short* rnnB = (unsigned short*)(ws + WS_RNNB);
  unsigned short* hB   = (unsigned short*)(ws + WS_HB16);

  k_attn<<<dim3(16, 64), 256, 0, stream>>>(enc, eW, eb, hidden, ws + WS_MS, ws + WS_CTX);
  k_combine<<<dim3(14, 64), 256, 0, stream>>>(ws + WS_MS, ws + WS_CTX, hidden, embt, x, rnnB);
  k_gates<<<512, 256, 0, stream>>>(rnnB, W_ih, W_hh, ws + WS_GP);
  k_lstm<<<256, 256, 0, stream>>>(ws + WS_GP, b_ih, b_hh, cell, out_h, out_c, hB);
  k_fc<<<1000, 128, 0, stream>>>(hB, fc_W, fc_b, preds);
}